// Round 2
// baseline (1208.430 us; speedup 1.0000x reference)
//
#include <hip/hip_runtime.h>
#include <hip/hip_cooperative_groups.h>
#include <math.h>

namespace cg = cooperative_groups;

#define NN 10000
#define NE 320000
#define DD 64
#define TILE 128
#define NTILE 79            // ceil(10000/128)
#define NPAD (NTILE * TILE) // 10112
#define PADROWS (NPAD - NN) // 112
#define NPAIRS (NTILE * (NTILE + 1) / 2)  // 3160 upper-triangle tile pairs
#define NB 1024             // cooperative grid: 4 blocks/CU x 256 CU

typedef __bf16 bf16x8 __attribute__((ext_vector_type(8)));
typedef float f32x4 __attribute__((ext_vector_type(4)));

// workspace layout (byte offsets, 16B-aligned)
#define OFF_CNT    0
#define OFF_FILL   40064
#define OFF_ROWPTR 80128
#define OFF_SRC    120192
#define OFF_DINV   1400192
#define OFF_H      1440256      // bpart aliases the head of h during scan
#define OFF_ZR1    4000256
#define OFF_ZR2    5294592

// ---------------------------------------------------------------------------
// Fused preprocessing: init -> count -> scan(A/B/C, +dinv) -> fill -> h -> agg
// One cooperative kernel, grid.sync() between stages.
__global__ __launch_bounds__(256, 4) void preproc_kernel(
    const float* __restrict__ z, const int* __restrict__ ei,
    const float* __restrict__ W, const float* __restrict__ bias,
    int* __restrict__ cnt, int* __restrict__ fill,
    int* __restrict__ rowptr, int* __restrict__ srcrow,
    float* __restrict__ dinv, float* __restrict__ h,
    int* __restrict__ bpart,
    __bf16* __restrict__ zr1, __bf16* __restrict__ zr2)
{
    cg::grid_group grid = cg::this_grid();
    const int tid = threadIdx.x;
    const int gtid = blockIdx.x * 256 + tid;
    const int gstride = NB * 256;

    __shared__ union {
        struct { float Ws[64 * 64]; float zs[4 * 64]; } hs;  // 17408 B
        int partial[256];
    } sm;

    // ---- stage 0: init (zero cnt/fill, zero zr pad rows)
    for (int i = gtid; i < NN; i += gstride) { cnt[i] = 0; fill[i] = 0; }
    for (int i = gtid; i < PADROWS * DD; i += gstride) {
        ((unsigned short*)zr1)[NN * DD + i] = 0;
        ((unsigned short*)zr2)[NN * DD + i] = 0;
    }
    grid.sync();

    // ---- stage 1: count (in-degree via atomics)
    for (int e = gtid; e < NE; e += gstride) atomicAdd(&cnt[ei[NE + e]], 1);
    grid.sync();

    // ---- stage 2: scan A — 40 blocks, 1 elem/thread, coalesced; fuse dinv
    if (blockIdx.x < 40) {
        const int idx = blockIdx.x * 256 + tid;
        const int myc = (idx < NN) ? cnt[idx] : 0;
        if (idx < NN) dinv[idx] = rsqrtf((float)myc + 1.0f);  // +1 self loop
        sm.partial[tid] = myc;
        __syncthreads();
        for (int off = 1; off < 256; off <<= 1) {
            int v = (tid >= off) ? sm.partial[tid - off] : 0;
            __syncthreads();
            sm.partial[tid] += v;
            __syncthreads();
        }
        if (idx < NN) rowptr[idx] = sm.partial[tid] - myc;  // exclusive-in-block
        if (tid == 255) bpart[blockIdx.x] = sm.partial[255];
    }
    grid.sync();

    // ---- stage 3: scan B — block 0 scans the 40 block sums
    if (blockIdx.x == 0) {
        const int v = (tid < 40) ? bpart[tid] : 0;
        sm.partial[tid] = v;
        __syncthreads();
        for (int off = 1; off < 256; off <<= 1) {
            int vv = (tid >= off) ? sm.partial[tid - off] : 0;
            __syncthreads();
            sm.partial[tid] += vv;
            __syncthreads();
        }
        if (tid < 40) bpart[tid] = sm.partial[tid] - v;  // exclusive
        if (tid == 0) rowptr[NN] = sm.partial[255];      // grand total
    }
    grid.sync();

    // ---- stage 4: scan C — add block offsets
    if (blockIdx.x < 40) {
        const int idx = blockIdx.x * 256 + tid;
        if (idx < NN) rowptr[idx] += bpart[blockIdx.x];
    }
    grid.sync();

    // ---- stage 5: fill CSR
    for (int e = gtid; e < NE; e += gstride) {
        int c = ei[NE + e];
        int pos = rowptr[c] + atomicAdd(&fill[c], 1);
        srcrow[pos] = ei[e];
    }
    grid.sync();

    // ---- stage 6: h = z @ W (W staged once per block, virtual-block loop)
    for (int i = tid; i < 4096; i += 256) sm.hs.Ws[i] = W[i];
    for (int vb = blockIdx.x; vb < NN / 4; vb += NB) {
        __syncthreads();   // Ws ready / previous zs consumers done
        sm.hs.zs[tid] = z[vb * 256 + tid];
        __syncthreads();
        const int r = tid >> 6, d = tid & 63;
        float acc = 0.0f;
#pragma unroll
        for (int k = 0; k < 64; k++)
            acc = fmaf(sm.hs.zs[r * 64 + k], sm.hs.Ws[k * 64 + d], acc);
        h[(vb * 4 + r) * DD + d] = acc;
    }
    grid.sync();

    // ---- stage 7: gather-aggregate + relu + bf16 hi/lo split
    const int lane = tid & 63;
    for (int g = blockIdx.x; g < (NN + 3) / 4; g += NB) {
        const int n = g * 4 + (tid >> 6);
        if (n < NN) {
            int s = __builtin_amdgcn_readfirstlane(rowptr[n]);
            int e = __builtin_amdgcn_readfirstlane(rowptr[n + 1]);
            const float dc = dinv[n];
            float acc = 0.0f;
            int i = s;
            for (; i + 1 < e; i += 2) {
                int r0 = __builtin_amdgcn_readfirstlane(srcrow[i]);
                int r1 = __builtin_amdgcn_readfirstlane(srcrow[i + 1]);
                float n0 = dinv[r0] * dc, n1 = dinv[r1] * dc;
                float h0 = h[r0 * DD + lane], h1 = h[r1 * DD + lane];
                acc = fmaf(h0, n0, acc);
                acc = fmaf(h1, n1, acc);
            }
            for (; i < e; i++) {
                int r = __builtin_amdgcn_readfirstlane(srcrow[i]);
                acc = fmaf(h[r * DD + lane], dinv[r] * dc, acc);
            }
            acc = fmaf(h[n * DD + lane], dc * dc, acc) + bias[lane];
            acc = acc > 0.0f ? acc : 0.0f;
            __bf16 hi = (__bf16)acc;
            float rem = acc - (float)hi;
            zr1[n * DD + lane] = hi;
            zr2[n * DD + lane] = (__bf16)rem;
        }
    }
}

// ---------------------------------------------------------------------------
// Fallback path (classic kernels) in case cooperative launch fails to enqueue.
__global__ void init_kernel(int* __restrict__ cnt, int* __restrict__ fill,
                            unsigned short* __restrict__ zr1,
                            unsigned short* __restrict__ zr2) {
    int tid = blockIdx.x * 256 + threadIdx.x;
    if (tid < NN) { cnt[tid] = 0; fill[tid] = 0; }
    if (tid < PADROWS * DD) {
        zr1[NN * DD + tid] = 0;
        zr2[NN * DD + tid] = 0;
    }
}

__global__ void count_kernel(const int* __restrict__ ei, int* __restrict__ cnt) {
    int e = blockIdx.x * 256 + threadIdx.x;
    if (e < NE) atomicAdd(&cnt[ei[NE + e]], 1);
}

__global__ void dinv_kernel(const int* __restrict__ cnt, float* __restrict__ dinv) {
    int i = blockIdx.x * 256 + threadIdx.x;
    if (i < NN) dinv[i] = rsqrtf((float)cnt[i] + 1.0f);
}

__global__ __launch_bounds__(256) void scan_kernel(const int* __restrict__ cnt,
                                                   int* __restrict__ rowptr) {
    __shared__ int partial[256];
    const int t = threadIdx.x;
    const int base = t * 40;
    int s = 0;
#pragma unroll 4
    for (int i = 0; i < 40; i++) {
        int idx = base + i;
        if (idx < NN) s += cnt[idx];
    }
    partial[t] = s;
    __syncthreads();
    for (int off = 1; off < 256; off <<= 1) {
        int v = (t >= off) ? partial[t - off] : 0;
        __syncthreads();
        partial[t] += v;
        __syncthreads();
    }
    int run = (t == 0) ? 0 : partial[t - 1];
    for (int i = 0; i < 40; i++) {
        int idx = base + i;
        if (idx < NN) { rowptr[idx] = run; run += cnt[idx]; }
    }
    if (t == 255) rowptr[NN] = partial[255];
}

__global__ void fill_kernel(const int* __restrict__ ei,
                            const int* __restrict__ rowptr,
                            int* __restrict__ fill, int* __restrict__ srcrow) {
    int e = blockIdx.x * 256 + threadIdx.x;
    if (e >= NE) return;
    int c = ei[NE + e];
    int pos = rowptr[c] + atomicAdd(&fill[c], 1);
    srcrow[pos] = ei[e];
}

__global__ __launch_bounds__(256) void h_kernel(const float* __restrict__ z,
                                                const float* __restrict__ W,
                                                float* __restrict__ h) {
    __shared__ float Ws[64 * 64];
    __shared__ float zs[4 * 64];
    const int tid = threadIdx.x;
    const int rbase = blockIdx.x * 4;
#pragma unroll
    for (int i = 0; i < 16; i++) Ws[i * 256 + tid] = W[i * 256 + tid];
    zs[tid] = z[rbase * DD + tid];
    __syncthreads();
    const int r = tid >> 6, d = tid & 63;
    float acc = 0.0f;
#pragma unroll
    for (int k = 0; k < 64; k++) acc = fmaf(zs[r * 64 + k], Ws[k * 64 + d], acc);
    h[(rbase + r) * DD + d] = acc;
}

__global__ __launch_bounds__(256) void agg_kernel(const int* __restrict__ rowptr,
                                                  const int* __restrict__ srcrow,
                                                  const float* __restrict__ dinv,
                                                  const float* __restrict__ h,
                                                  const float* __restrict__ b,
                                                  __bf16* __restrict__ zr1,
                                                  __bf16* __restrict__ zr2) {
    const int lane = threadIdx.x & 63;
    const int n = blockIdx.x * 4 + (threadIdx.x >> 6);
    if (n >= NN) return;
    int s = __builtin_amdgcn_readfirstlane(rowptr[n]);
    int e = __builtin_amdgcn_readfirstlane(rowptr[n + 1]);
    const float dc = dinv[n];
    float acc = 0.0f;
    int i = s;
    for (; i + 1 < e; i += 2) {
        int r0 = __builtin_amdgcn_readfirstlane(srcrow[i]);
        int r1 = __builtin_amdgcn_readfirstlane(srcrow[i + 1]);
        float n0 = dinv[r0] * dc, n1 = dinv[r1] * dc;
        float h0 = h[r0 * DD + lane], h1 = h[r1 * DD + lane];
        acc = fmaf(h0, n0, acc);
        acc = fmaf(h1, n1, acc);
    }
    for (; i < e; i++) {
        int r = __builtin_amdgcn_readfirstlane(srcrow[i]);
        acc = fmaf(h[r * DD + lane], dinv[r] * dc, acc);
    }
    acc = fmaf(h[n * DD + lane], dc * dc, acc) + b[lane];
    acc = acc > 0.0f ? acc : 0.0f;
    __bf16 hi = (__bf16)acc;
    float rem = acc - (float)hi;
    zr1[n * DD + lane] = hi;
    zr2[n * DD + lane] = (__bf16)rem;
}

// ---------------------------------------------------------------------------
// C = zr @ zr^T, symmetric: upper-triangle 128x128 tiles only, in-place +
// transposed-mirror stores. (Block-count A/B proved gemm compute <10us; left
// unchanged this round.)
__global__ __launch_bounds__(256) void gemm_kernel(const __bf16* __restrict__ z1,
                                                   const __bf16* __restrict__ z2,
                                                   float* __restrict__ C) {
    const int t = blockIdx.x;
    const float ff = (float)(2 * NTILE + 1);
    int bi = (int)((ff - sqrtf(ff * ff - 8.0f * (float)t)) * 0.5f);
    while ((bi + 1) * NTILE - ((bi + 1) * bi) / 2 <= t) bi++;
    while (bi * NTILE - (bi * (bi - 1)) / 2 > t) bi--;
    const int bj = bi + (t - (bi * NTILE - (bi * (bi - 1)) / 2));

    const int tid = threadIdx.x;
    const int lane = tid & 63;
    const int w = tid >> 6;
    const int wr = w >> 1, wc = w & 1;
    const int m16 = lane & 15;
    const int kq = lane >> 4;
    const int rbase = bi * TILE + wr * 64;
    const int cbase = bj * TILE + wc * 64;

    f32x4 acc[4][4] = {};

    for (int kk = 0; kk < 2; kk++) {
        const int ko = kk * 32 + kq * 8;
        bf16x8 a1[4], a2[4], b1[4], b2[4];
#pragma unroll
        for (int tt = 0; tt < 4; tt++) {
            const int ar = rbase + tt * 16 + m16;
            const int br = cbase + tt * 16 + m16;
            a1[tt] = *(const bf16x8*)&z1[ar * DD + ko];
            a2[tt] = *(const bf16x8*)&z2[ar * DD + ko];
            b1[tt] = *(const bf16x8*)&z1[br * DD + ko];
            b2[tt] = *(const bf16x8*)&z2[br * DD + ko];
        }
#pragma unroll
        for (int mt = 0; mt < 4; mt++)
#pragma unroll
            for (int nt = 0; nt < 4; nt++) {
                acc[mt][nt] = __builtin_amdgcn_mfma_f32_16x16x32_bf16(a2[mt], b1[nt], acc[mt][nt], 0, 0, 0);
                acc[mt][nt] = __builtin_amdgcn_mfma_f32_16x16x32_bf16(a1[mt], b2[nt], acc[mt][nt], 0, 0, 0);
                acc[mt][nt] = __builtin_amdgcn_mfma_f32_16x16x32_bf16(a1[mt], b1[nt], acc[mt][nt], 0, 0, 0);
            }
    }

#pragma unroll
    for (int mt = 0; mt < 4; mt++) {
        const int row0 = rbase + mt * 16 + kq * 4;
#pragma unroll
        for (int nt = 0; nt < 4; nt++) {
            const int col = cbase + nt * 16 + m16;
            if (col < NN) {
#pragma unroll
                for (int r = 0; r < 4; r++) {
                    const int row = row0 + r;
                    if (row < NN) C[(size_t)row * NN + col] = acc[mt][nt][r];
                }
            }
        }
    }

    if (bi != bj) {
#pragma unroll
        for (int mt = 0; mt < 4; mt++) {
            const int tcol0 = rbase + mt * 16 + kq * 4;
            if (tcol0 < NN) {
#pragma unroll
                for (int nt = 0; nt < 4; nt++) {
                    const int trow = cbase + nt * 16 + m16;
                    if (trow < NN)
                        *(f32x4*)&C[(size_t)trow * NN + tcol0] = acc[mt][nt];
                }
            }
        }
    }
}

// ---------------------------------------------------------------------------
extern "C" void kernel_launch(void* const* d_in, const int* in_sizes, int n_in,
                              void* d_out, int out_size, void* d_ws, size_t ws_size,
                              hipStream_t stream) {
    const float* z = (const float*)d_in[0];
    const int* ei = (const int*)d_in[1];  // [2, E]: row=ei[0:E], col=ei[E:2E]
    const float* W = (const float*)d_in[2];
    const float* b = (const float*)d_in[3];
    float* C = (float*)d_out;

    char* ws = (char*)d_ws;
    int* cnt = (int*)(ws + OFF_CNT);
    int* fill = (int*)(ws + OFF_FILL);
    int* rowptr = (int*)(ws + OFF_ROWPTR);
    int* srcrow = (int*)(ws + OFF_SRC);
    float* dinv = (float*)(ws + OFF_DINV);
    float* h = (float*)(ws + OFF_H);
    int* bpart = (int*)(ws + OFF_H);  // aliases h; consumed before h written
    __bf16* zr1 = (__bf16*)(ws + OFF_ZR1);
    __bf16* zr2 = (__bf16*)(ws + OFF_ZR2);

    void* args[] = { (void*)&z, (void*)&ei, (void*)&W, (void*)&b,
                     (void*)&cnt, (void*)&fill, (void*)&rowptr, (void*)&srcrow,
                     (void*)&dinv, (void*)&h, (void*)&bpart,
                     (void*)&zr1, (void*)&zr2 };
    hipError_t err = hipLaunchCooperativeKernel((void*)preproc_kernel,
                                                dim3(NB), dim3(256),
                                                args, 0, stream);
    if (err != hipSuccess) {
        // fallback: classic 7-kernel chain
        init_kernel<<<(NN + 255) / 256, 256, 0, stream>>>(cnt, fill,
                                                          (unsigned short*)zr1,
                                                          (unsigned short*)zr2);
        count_kernel<<<(NE + 255) / 256, 256, 0, stream>>>(ei, cnt);
        dinv_kernel<<<(NN + 255) / 256, 256, 0, stream>>>(cnt, dinv);
        scan_kernel<<<1, 256, 0, stream>>>(cnt, rowptr);
        fill_kernel<<<(NE + 255) / 256, 256, 0, stream>>>(ei, rowptr, fill, srcrow);
        h_kernel<<<NN / 4, 256, 0, stream>>>(z, W, h);
        agg_kernel<<<(NN + 3) / 4, 256, 0, stream>>>(rowptr, srcrow, dinv, h, b, zr1, zr2);
    }

    gemm_kernel<<<NPAIRS, 256, 0, stream>>>(zr1, zr2, C);
}

// Round 3
// 538.835 us; speedup vs baseline: 2.2427x; 2.2427x over previous
//
#include <hip/hip_runtime.h>
#include <math.h>

#define NN 10000
#define NE 320000
#define DD 64
#define TILE 128
#define NTILE 79            // ceil(10000/128)
#define NPAD (NTILE * TILE) // 10112
#define PADROWS (NPAD - NN) // 112
#define NPAIRS (NTILE * (NTILE + 1) / 2)  // 3160 upper-triangle tile pairs

typedef __bf16 bf16x8 __attribute__((ext_vector_type(8)));
typedef float f32x4 __attribute__((ext_vector_type(4)));

// workspace layout (byte offsets, 16B-aligned)
#define OFF_CNT    0
#define OFF_FILL   40064
#define OFF_ROWPTR 80128
#define OFF_SRC    120192
#define OFF_DINV   1400192
#define OFF_H      1440256
#define OFF_ZR1    4000256
#define OFF_ZR2    5294592

// ---------------------------------------------------------------------------
__global__ void init_kernel(int* __restrict__ cnt, int* __restrict__ fill,
                            unsigned short* __restrict__ zr1,
                            unsigned short* __restrict__ zr2) {
    int tid = blockIdx.x * 256 + threadIdx.x;
    if (tid < NN) { cnt[tid] = 0; fill[tid] = 0; }
    if (tid < PADROWS * DD) {
        zr1[NN * DD + tid] = 0;
        zr2[NN * DD + tid] = 0;
    }
}

__global__ void count_kernel(const int* __restrict__ ei, int* __restrict__ cnt) {
    int e = blockIdx.x * 256 + threadIdx.x;
    if (e < NE) atomicAdd(&cnt[ei[NE + e]], 1);
}

__global__ void dinv_kernel(const int* __restrict__ cnt, float* __restrict__ dinv) {
    int i = blockIdx.x * 256 + threadIdx.x;
    if (i < NN) dinv[i] = rsqrtf((float)cnt[i] + 1.0f);  // +1 self loop
}

// single-block exclusive scan of cnt[NN] -> rowptr[NN+1]
__global__ __launch_bounds__(256) void scan_kernel(const int* __restrict__ cnt,
                                                   int* __restrict__ rowptr) {
    __shared__ int partial[256];
    const int t = threadIdx.x;
    const int base = t * 40;  // 256*40 = 10240 >= NN
    int s = 0;
#pragma unroll 4
    for (int i = 0; i < 40; i++) {
        int idx = base + i;
        if (idx < NN) s += cnt[idx];
    }
    partial[t] = s;
    __syncthreads();
    for (int off = 1; off < 256; off <<= 1) {
        int v = (t >= off) ? partial[t - off] : 0;
        __syncthreads();
        partial[t] += v;
        __syncthreads();
    }
    int run = (t == 0) ? 0 : partial[t - 1];
    for (int i = 0; i < 40; i++) {
        int idx = base + i;
        if (idx < NN) { rowptr[idx] = run; run += cnt[idx]; }
    }
    if (t == 255) rowptr[NN] = partial[255];
}

__global__ void fill_kernel(const int* __restrict__ ei,
                            const int* __restrict__ rowptr,
                            int* __restrict__ fill, int* __restrict__ srcrow) {
    int e = blockIdx.x * 256 + threadIdx.x;
    if (e >= NE) return;
    int c = ei[NE + e];
    int pos = rowptr[c] + atomicAdd(&fill[c], 1);
    srcrow[pos] = ei[e];
}

// h = z @ W   (4 rows per block, W staged in LDS)
__global__ __launch_bounds__(256) void h_kernel(const float* __restrict__ z,
                                                const float* __restrict__ W,
                                                float* __restrict__ h) {
    __shared__ float Ws[64 * 64];
    __shared__ float zs[4 * 64];
    const int tid = threadIdx.x;
    const int rbase = blockIdx.x * 4;
#pragma unroll
    for (int i = 0; i < 16; i++) Ws[i * 256 + tid] = W[i * 256 + tid];
    zs[tid] = z[rbase * DD + tid];
    __syncthreads();
    const int r = tid >> 6, d = tid & 63;
    float acc = 0.0f;
#pragma unroll
    for (int k = 0; k < 64; k++) acc = fmaf(zs[r * 64 + k], Ws[k * 64 + d], acc);
    h[(rbase + r) * DD + d] = acc;
}

// gather-aggregate: one wave per destination node, lane = feature dim.
__global__ __launch_bounds__(256) void agg_kernel(const int* __restrict__ rowptr,
                                                  const int* __restrict__ srcrow,
                                                  const float* __restrict__ dinv,
                                                  const float* __restrict__ h,
                                                  const float* __restrict__ b,
                                                  __bf16* __restrict__ zr1,
                                                  __bf16* __restrict__ zr2) {
    const int lane = threadIdx.x & 63;
    const int n = blockIdx.x * 4 + (threadIdx.x >> 6);
    if (n >= NN) return;
    int s = __builtin_amdgcn_readfirstlane(rowptr[n]);
    int e = __builtin_amdgcn_readfirstlane(rowptr[n + 1]);
    const float dc = dinv[n];
    float acc = 0.0f;
    int i = s;
    for (; i + 1 < e; i += 2) {
        int r0 = __builtin_amdgcn_readfirstlane(srcrow[i]);
        int r1 = __builtin_amdgcn_readfirstlane(srcrow[i + 1]);
        float n0 = dinv[r0] * dc, n1 = dinv[r1] * dc;
        float h0 = h[r0 * DD + lane], h1 = h[r1 * DD + lane];
        acc = fmaf(h0, n0, acc);
        acc = fmaf(h1, n1, acc);
    }
    for (; i < e; i++) {
        int r = __builtin_amdgcn_readfirstlane(srcrow[i]);
        acc = fmaf(h[r * DD + lane], dinv[r] * dc, acc);
    }
    acc = fmaf(h[n * DD + lane], dc * dc, acc) + b[lane];
    acc = acc > 0.0f ? acc : 0.0f;
    __bf16 hi = (__bf16)acc;
    float rem = acc - (float)hi;
    zr1[n * DD + lane] = hi;
    zr2[n * DD + lane] = (__bf16)rem;
}

// ---------------------------------------------------------------------------
// C = zr @ zr^T, symmetric: 3160 upper-triangle 128x128 tile-pairs.
// Off-diagonal pairs compute BOTH orientations via swapped MFMA operands
// (compute is free per round-1 A/B); ALL stores go through a per-wave LDS
// half-tile so each global_store_dwordx4 writes 4 rows x 256B contiguous
// bursts (full 128B lines), nontemporal to keep zr resident in L2.
// Verified C/D layout: element(i,j) of tile = acc[mt][nt][r] with
// i = mt*16 + (lane>>4)*4 + r, j = nt*16 + (lane&15).
__global__ __launch_bounds__(256) void gemm_kernel(const __bf16* __restrict__ z1,
                                                   const __bf16* __restrict__ z2,
                                                   float* __restrict__ C) {
    __shared__ float T[4][32][64];  // per-wave private 32x64 half-tile, 32 KB

    // triangular decode: block t -> (bi, bj), bi <= bj
    const int t = blockIdx.x;
    const float ff = (float)(2 * NTILE + 1);
    int bi = (int)((ff - sqrtf(ff * ff - 8.0f * (float)t)) * 0.5f);
    while ((bi + 1) * NTILE - ((bi + 1) * bi) / 2 <= t) bi++;
    while (bi * NTILE - (bi * (bi - 1)) / 2 > t) bi--;
    const int bj = bi + (t - (bi * NTILE - (bi * (bi - 1)) / 2));

    const int tid = threadIdx.x;
    const int lane = tid & 63;
    const int w = tid >> 6;
    const int wr = w >> 1, wc = w & 1;
    const int m16 = lane & 15;
    const int kq = lane >> 4;

    const int norient = (bi == bj) ? 1 : 2;
    for (int o = 0; o < norient; o++) {
        // A-band = output rows, B-band = output cols; o=1 swaps bands AND
        // wave quadrants so the 4 waves tile the mirrored 128x128 region.
        const int Ab = (o == 0 ? bi : bj) * TILE + (o == 0 ? wr : wc) * 64;
        const int Bb = (o == 0 ? bj : bi) * TILE + (o == 0 ? wc : wr) * 64;

        f32x4 acc[4][4] = {};
        for (int kk = 0; kk < 2; kk++) {
            const int ko = kk * 32 + kq * 8;
            bf16x8 a1[4], a2[4], b1[4], b2[4];
#pragma unroll
            for (int tt = 0; tt < 4; tt++) {
                const int ar = Ab + tt * 16 + m16;
                const int br = Bb + tt * 16 + m16;
                a1[tt] = *(const bf16x8*)&z1[ar * DD + ko];
                a2[tt] = *(const bf16x8*)&z2[ar * DD + ko];
                b1[tt] = *(const bf16x8*)&z1[br * DD + ko];
                b2[tt] = *(const bf16x8*)&z2[br * DD + ko];
            }
#pragma unroll
            for (int mt = 0; mt < 4; mt++)
#pragma unroll
                for (int nt = 0; nt < 4; nt++) {
                    acc[mt][nt] = __builtin_amdgcn_mfma_f32_16x16x32_bf16(a2[mt], b1[nt], acc[mt][nt], 0, 0, 0);
                    acc[mt][nt] = __builtin_amdgcn_mfma_f32_16x16x32_bf16(a1[mt], b2[nt], acc[mt][nt], 0, 0, 0);
                    acc[mt][nt] = __builtin_amdgcn_mfma_f32_16x16x32_bf16(a1[mt], b1[nt], acc[mt][nt], 0, 0, 0);
                }
        }

        // epilogue: two half-tiles (rows 0..31, 32..63) through LDS
        for (int hf = 0; hf < 2; hf++) {
            __syncthreads();  // LDS region reusable (prev phase's reads done)
#pragma unroll
            for (int mh = 0; mh < 2; mh++) {
                const int mt = hf * 2 + mh;
                const int i0 = mh * 16 + kq * 4;
#pragma unroll
                for (int nt = 0; nt < 4; nt++) {
                    const int j = nt * 16 + m16;
#pragma unroll
                    for (int r = 0; r < 4; r++)
                        T[w][i0 + r][j] = acc[mt][nt][r];
                }
            }
            __syncthreads();  // includes waitcnt: LDS writes visible
            const int rg = lane >> 4;        // 0..3
            const int c0 = (lane & 15) * 4;  // 0..60
#pragma unroll
            for (int it = 0; it < 8; it++) {
                const int i = it * 4 + rg;           // 0..31
                const int grow = Ab + hf * 32 + i;   // global row
                const int gcol = Bb + c0;            // global col (mult of 4)
                if (grow < NN && gcol < NN) {
                    f32x4 v = *(const f32x4*)&T[w][i][c0];
                    __builtin_nontemporal_store(v, (f32x4*)&C[(size_t)grow * NN + gcol]);
                }
            }
        }
    }
}

// ---------------------------------------------------------------------------
extern "C" void kernel_launch(void* const* d_in, const int* in_sizes, int n_in,
                              void* d_out, int out_size, void* d_ws, size_t ws_size,
                              hipStream_t stream) {
    const float* z = (const float*)d_in[0];
    const int* ei = (const int*)d_in[1];  // [2, E]: row=ei[0:E], col=ei[E:2E]
    const float* W = (const float*)d_in[2];
    const float* b = (const float*)d_in[3];
    float* C = (float*)d_out;

    char* ws = (char*)d_ws;
    int* cnt = (int*)(ws + OFF_CNT);
    int* fill = (int*)(ws + OFF_FILL);
    int* rowptr = (int*)(ws + OFF_ROWPTR);
    int* srcrow = (int*)(ws + OFF_SRC);
    float* dinv = (float*)(ws + OFF_DINV);
    float* h = (float*)(ws + OFF_H);
    __bf16* zr1 = (__bf16*)(ws + OFF_ZR1);
    __bf16* zr2 = (__bf16*)(ws + OFF_ZR2);

    init_kernel<<<(NN + 255) / 256, 256, 0, stream>>>(cnt, fill,
                                                      (unsigned short*)zr1,
                                                      (unsigned short*)zr2);
    count_kernel<<<(NE + 255) / 256, 256, 0, stream>>>(ei, cnt);
    dinv_kernel<<<(NN + 255) / 256, 256, 0, stream>>>(cnt, dinv);
    scan_kernel<<<1, 256, 0, stream>>>(cnt, rowptr);
    fill_kernel<<<(NE + 255) / 256, 256, 0, stream>>>(ei, rowptr, fill, srcrow);
    h_kernel<<<NN / 4, 256, 0, stream>>>(z, W, h);
    agg_kernel<<<(NN + 3) / 4, 256, 0, stream>>>(rowptr, srcrow, dinv, h, b, zr1, zr2);

    gemm_kernel<<<NPAIRS, 256, 0, stream>>>(zr1, zr2, C);
}